// Round 3
// baseline (437.184 us; speedup 1.0000x reference)
//
#include <hip/hip_runtime.h>

#define N_NODES 100000
#define N_EDGES 1600000
#define IN_DIM 128
#define OUT_DIM 32

#define BROWS 128                 // rows per bucket (pow2: bucket = row>>7)
#define NB 782                    // ceil(100000/128)
#define NBP 784                   // padded (multiple of 4)
#define EPB 4096                  // edges per bin_edges block

// -------- kernel 1: support = X @ W --------
__global__ __launch_bounds__(256) void gemm_support(
    const float* __restrict__ x, const float* __restrict__ w,
    float* __restrict__ support) {
  __shared__ float ws[IN_DIM][OUT_DIM];   // 16 KB
  __shared__ float xs[8][IN_DIM];         // 4 KB
  const int tid = threadIdx.x;

  for (int i = tid; i < IN_DIM * OUT_DIM; i += 256)
    ws[i / OUT_DIM][i % OUT_DIM] = w[i];

  const int row0 = blockIdx.x * 8;
  for (int i = tid; i < 8 * IN_DIM; i += 256) {
    const int r = i / IN_DIM, k = i % IN_DIM;
    const int row = row0 + r;
    xs[r][k] = (row < N_NODES) ? x[(long long)row * IN_DIM + k] : 0.f;
  }
  __syncthreads();

  const int r = tid >> 5;
  const int c = tid & 31;
  const int row = row0 + r;
  if (row >= N_NODES) return;

  float acc = 0.f;
#pragma unroll
  for (int k = 0; k < IN_DIM; ++k)
    acc = fmaf(xs[r][k], ws[k][c], acc);
  support[(long long)row * OUT_DIM + c] = acc;
}

// -------- kernel 2: bucket histogram (LDS pre-aggregated) --------
__global__ __launch_bounds__(256) void hist_buckets(
    const int* __restrict__ rows, int* __restrict__ gHist) {
  __shared__ int h[NBP];
  const int t = threadIdx.x;
  for (int b = t; b < NBP; b += 256) h[b] = 0;
  __syncthreads();
  const long long stride = (long long)gridDim.x * 256;
  for (long long e = (long long)blockIdx.x * 256 + t; e < N_EDGES; e += stride)
    atomicAdd(&h[rows[e] >> 7], 1);
  __syncthreads();
  for (int b = t; b < NBP; b += 256)
    if (h[b]) atomicAdd(&gHist[b], h[b]);
}

// -------- kernel 3: exclusive scan of bucket counts --------
__global__ __launch_bounds__(1024) void scan_buckets(
    const int* __restrict__ gHist, int* __restrict__ segStart,
    int* __restrict__ gCursor) {
  __shared__ int sm[1024];
  const int t = threadIdx.x;
  const int v = (t < NBP) ? gHist[t] : 0;
  sm[t] = v;
  __syncthreads();
  for (int off = 1; off < 1024; off <<= 1) {
    int u = (t >= off) ? sm[t - off] : 0;
    __syncthreads();
    sm[t] += u;
    __syncthreads();
  }
  if (t < NBP) {
    const int ex = sm[t] - v;
    segStart[t] = ex;
    gCursor[t] = ex;
  }
  if (t == NBP - 1) segStart[NBP] = sm[t];
}

// -------- kernel 4: bin edges into bucket segments (LDS-staged flush) -------
__global__ __launch_bounds__(256) void bin_edges(
    const int* __restrict__ rows, const int* __restrict__ cols,
    const float* __restrict__ vals, int* __restrict__ gCursor,
    unsigned long long* __restrict__ gKV) {
  __shared__ unsigned long long kvS[EPB];     // 32 KB
  __shared__ unsigned short bucketOf[EPB];    // 8 KB
  __shared__ int hist[NBP];                   // 3136 B
  __shared__ int base[NBP];
  __shared__ int cursor[NBP];
  __shared__ int csum[256];
  const int t = threadIdx.x;
  const long long b0 = (long long)blockIdx.x * EPB;
  const int nTot = (int)min((long long)EPB, (long long)N_EDGES - b0);

  for (int b = t; b < NBP; b += 256) hist[b] = 0;
  __syncthreads();

  // pass 1: local histogram
  for (int i = 0; i < EPB / 256; ++i) {
    const int j = i * 256 + t;
    if (j < nTot) atomicAdd(&hist[rows[b0 + j] >> 7], 1);
  }
  __syncthreads();

  // scan hist -> base (exclusive), 4 buckets per thread
  {
    int h0 = 0, h1 = 0, h2 = 0, h3 = 0, s = 0;
    if (t < NBP / 4) {
      h0 = hist[4 * t]; h1 = hist[4 * t + 1];
      h2 = hist[4 * t + 2]; h3 = hist[4 * t + 3];
      s = h0 + h1 + h2 + h3;
    }
    csum[t] = s;
    __syncthreads();
    for (int off = 1; off < 256; off <<= 1) {
      int u = (t >= off) ? csum[t - off] : 0;
      __syncthreads();
      csum[t] += u;
      __syncthreads();
    }
    if (t < NBP / 4) {
      const int b = csum[t] - s;
      base[4 * t] = b;
      base[4 * t + 1] = b + h0;
      base[4 * t + 2] = b + h0 + h1;
      base[4 * t + 3] = b + h0 + h1 + h2;
      cursor[4 * t] = base[4 * t];
      cursor[4 * t + 1] = base[4 * t + 1];
      cursor[4 * t + 2] = base[4 * t + 2];
      cursor[4 * t + 3] = base[4 * t + 3];
    }
  }
  __syncthreads();

  // pass 2: scatter records into bucket-ordered LDS stage
  for (int i = 0; i < EPB / 256; ++i) {
    const int j = i * 256 + t;
    if (j < nTot) {
      const long long e = b0 + j;
      const int r = rows[e];
      const int bkt = r >> 7;
      const unsigned key = ((unsigned)(r & 127) << 17) | (unsigned)cols[e];
      const int pos = atomicAdd(&cursor[bkt], 1);
      kvS[pos] = ((unsigned long long)__float_as_uint(vals[e]) << 32) | key;
      bucketOf[pos] = (unsigned short)bkt;
    }
  }
  __syncthreads();

  // reserve global space per bucket (cursor now = absolute dst base)
  for (int b = t; b < NBP; b += 256) {
    const int cnt = hist[b];
    cursor[b] = (cnt > 0) ? atomicAdd(&gCursor[b], cnt) : 0;
  }
  __syncthreads();

  // flush: coalesced runs per bucket
  for (int i = t; i < nTot; i += 256) {
    const int bkt = bucketOf[i];
    gKV[(long long)cursor[bkt] + (i - base[bkt])] = kvS[i];
  }
}

// -------- kernel 5: per-bucket dense SpMM in LDS, zero global atomics ------
__global__ __launch_bounds__(256) void spmm_bucket(
    const int* __restrict__ segStart, const unsigned long long* __restrict__ gKV,
    const float* __restrict__ support, const float* __restrict__ bias,
    float* __restrict__ out) {
  __shared__ float accum[BROWS * OUT_DIM];   // 16 KB
  const int t = threadIdx.x;
  for (int j = t; j < BROWS * OUT_DIM; j += 256) accum[j] = 0.f;

  const int b = blockIdx.x;
  const int s = segStart[b];
  const int e = segStart[b + 1];
  __syncthreads();

  const int lane = t & 63;
  const int w = t >> 6;        // wave 0..3
  const int half = lane >> 5;  // 0/1
  const int d = lane & 31;     // output dim
#pragma unroll 2
  for (int idx = s + w * 2 + half; idx < e; idx += 8) {
    const unsigned long long kv = gKV[idx];
    const unsigned key = (unsigned)kv;
    const int c = key & 0x1FFFF;
    const int rl = key >> 17;
    const float v = __uint_as_float((unsigned)(kv >> 32));
    atomicAdd(&accum[rl * OUT_DIM + d], v * support[(long long)c * OUT_DIM + d]);
  }
  __syncthreads();

  const float bv = bias[t & 31];
  const int row0 = b << 7;
  for (int j = t; j < BROWS * OUT_DIM; j += 256) {
    const int row = row0 + (j >> 5);
    if (row < N_NODES) out[(long long)row * OUT_DIM + (j & 31)] = accum[j] + bv;
  }
}

extern "C" void kernel_launch(void* const* d_in, const int* in_sizes, int n_in,
                              void* d_out, int out_size, void* d_ws, size_t ws_size,
                              hipStream_t stream) {
  const float* x        = (const float*)d_in[0];
  const int*   adj_rows = (const int*)d_in[1];
  const int*   adj_cols = (const int*)d_in[2];
  const float* adj_vals = (const float*)d_in[3];
  const float* weight   = (const float*)d_in[4];
  const float* bias     = (const float*)d_in[5];
  float* out = (float*)d_out;

  // ---- workspace layout (~25.6 MB) ----
  char* wsp = (char*)d_ws;
  float* support = (float*)wsp;                                 // 12,800,000 B
  unsigned long long* gKV = (unsigned long long*)(wsp + 12800000); // 12,800,000 B
  int* segStart = (int*)(wsp + 25600000);                       // (NBP+1)*4, pad 3200
  int* gHist    = (int*)(wsp + 25603200);                       // 3136 -> 3200
  int* gCursor  = (int*)(wsp + 25606400);                       // 3136

  hipMemsetAsync(gHist, 0, NBP * sizeof(int), stream);

  gemm_support<<<(N_NODES + 7) / 8, 256, 0, stream>>>(x, weight, support);
  hist_buckets<<<256, 256, 0, stream>>>(adj_rows, gHist);
  scan_buckets<<<1, 1024, 0, stream>>>(gHist, segStart, gCursor);
  bin_edges<<<(N_EDGES + EPB - 1) / EPB, 256, 0, stream>>>(
      adj_rows, adj_cols, adj_vals, gCursor, gKV);
  spmm_bucket<<<NB, 256, 0, stream>>>(segStart, gKV, support, bias, out);
}

// Round 4
// 284.602 us; speedup vs baseline: 1.5361x; 1.5361x over previous
//
#include <hip/hip_runtime.h>

#define N_NODES 100000
#define N_EDGES 1600000
#define IN_DIM 128
#define OUT_DIM 32

#define NGROUPS 8
#define ROWS_PER_G 12500          // 8 * 12500 = 100000 exactly
#define EPB 4096                  // edges per bin8 block
#define BPG 256                   // spmm8 blocks per group (grid = 2048)

// -------- kernel 1: support = X @ W --------
__global__ __launch_bounds__(256) void gemm_support(
    const float* __restrict__ x, const float* __restrict__ w,
    float* __restrict__ support) {
  __shared__ float ws[IN_DIM][OUT_DIM];   // 16 KB
  __shared__ float xs[8][IN_DIM];         // 4 KB
  const int tid = threadIdx.x;

  for (int i = tid; i < IN_DIM * OUT_DIM; i += 256)
    ws[i / OUT_DIM][i % OUT_DIM] = w[i];

  const int row0 = blockIdx.x * 8;
  for (int i = tid; i < 8 * IN_DIM; i += 256) {
    const int r = i / IN_DIM, k = i % IN_DIM;
    const int row = row0 + r;
    xs[r][k] = (row < N_NODES) ? x[(long long)row * IN_DIM + k] : 0.f;
  }
  __syncthreads();

  const int r = tid >> 5;
  const int c = tid & 31;
  const int row = row0 + r;
  if (row >= N_NODES) return;

  float acc = 0.f;
#pragma unroll
  for (int k = 0; k < IN_DIM; ++k)
    acc = fmaf(xs[r][k], ws[k][c], acc);
  support[(long long)row * OUT_DIM + c] = acc;
}

// -------- kernel 2: out[i] = bias[i % 32] --------
__global__ __launch_bounds__(256) void init_out(
    const float* __restrict__ bias, float* __restrict__ out) {
  const int i = blockIdx.x * 256 + threadIdx.x;
  if (i < N_NODES * OUT_DIM) out[i] = bias[i & (OUT_DIM - 1)];
}

// -------- kernel 3: 8-group histogram (ballot-aggregated, no contention) ----
__global__ __launch_bounds__(256) void hist8(
    const int* __restrict__ rows, int* __restrict__ gHist) {
  const int t = threadIdx.x;
  const int lane = t & 63;
  int cnt[NGROUPS];
#pragma unroll
  for (int k = 0; k < NGROUPS; ++k) cnt[k] = 0;
  const long long stride = (long long)gridDim.x * 256;
  for (long long e = (long long)blockIdx.x * 256 + t; e < N_EDGES; e += stride) {
    const int g = rows[e] / ROWS_PER_G;
#pragma unroll
    for (int k = 0; k < NGROUPS; ++k)
      cnt[k] += (int)__popcll(__ballot(g == k));   // uniform across wave
  }
  if (lane < NGROUPS && cnt[0] + 1 > 0) {
    // lane k adds group k's wave-total (cnt[] is wave-uniform)
    int v;
    switch (lane) {
      case 0: v = cnt[0]; break; case 1: v = cnt[1]; break;
      case 2: v = cnt[2]; break; case 3: v = cnt[3]; break;
      case 4: v = cnt[4]; break; case 5: v = cnt[5]; break;
      case 6: v = cnt[6]; break; default: v = cnt[7]; break;
    }
    if (v) atomicAdd(&gHist[lane], v);
  }
}

// -------- kernel 4: scan of 8 group counts --------
__global__ void scan8(const int* __restrict__ gHist, int* __restrict__ segStart,
                      int* __restrict__ gCursor) {
  if (threadIdx.x == 0) {
    int s = 0;
    for (int g = 0; g < NGROUPS; ++g) {
      segStart[g] = s;
      gCursor[g] = s;
      s += gHist[g];
    }
    segStart[NGROUPS] = s;
  }
}

// -------- kernel 5: bin edges into 8 group segments (coalesced flush) -------
__global__ __launch_bounds__(256) void bin8(
    const int* __restrict__ rows, const int* __restrict__ cols,
    const float* __restrict__ vals, int* __restrict__ gCursor,
    unsigned long long* __restrict__ gKV) {
  __shared__ unsigned long long kvS[EPB];   // 32 KB
  __shared__ unsigned char bucketOf[EPB];   // 4 KB
  __shared__ int hist[NGROUPS];
  __shared__ int base[NGROUPS];
  __shared__ int cursor[NGROUPS];
  __shared__ int gbase[NGROUPS];
  const int t = threadIdx.x;
  const int lane = t & 63;
  const unsigned long long lt = (1ULL << lane) - 1ULL;
  const long long b0 = (long long)blockIdx.x * EPB;
  const int nTot = (int)min((long long)EPB, (long long)N_EDGES - b0);

  if (t < NGROUPS) hist[t] = 0;
  __syncthreads();

  // pass 1: wave-aggregated histogram
  {
    int cnt[NGROUPS];
#pragma unroll
    for (int k = 0; k < NGROUPS; ++k) cnt[k] = 0;
    for (int i = 0; i < EPB / 256; ++i) {
      const int j = i * 256 + t;
      const int g = (j < nTot) ? (rows[b0 + j] / ROWS_PER_G) : -1;
#pragma unroll
      for (int k = 0; k < NGROUPS; ++k)
        cnt[k] += (int)__popcll(__ballot(g == k));
    }
    if (lane < NGROUPS) {
      int v;
      switch (lane) {
        case 0: v = cnt[0]; break; case 1: v = cnt[1]; break;
        case 2: v = cnt[2]; break; case 3: v = cnt[3]; break;
        case 4: v = cnt[4]; break; case 5: v = cnt[5]; break;
        case 6: v = cnt[6]; break; default: v = cnt[7]; break;
      }
      if (v) atomicAdd(&hist[lane], v);
    }
  }
  __syncthreads();
  if (t == 0) {
    int s = 0;
    for (int g = 0; g < NGROUPS; ++g) {
      base[g] = s;
      cursor[g] = s;
      s += hist[g];
    }
  }
  __syncthreads();

  // pass 2: wave-aggregated scatter into bucket-ordered LDS stage
  for (int i = 0; i < EPB / 256; ++i) {
    const int j = i * 256 + t;
    int bkt = -1;
    unsigned long long kv = 0;
    if (j < nTot) {
      const long long e = b0 + j;
      const int r = rows[e];
      bkt = r / ROWS_PER_G;
      const unsigned key =
          ((unsigned)(r - bkt * ROWS_PER_G) << 17) | (unsigned)cols[e];
      kv = ((unsigned long long)__float_as_uint(vals[e]) << 32) | key;
    }
    int pos = -1;
#pragma unroll
    for (int g = 0; g < NGROUPS; ++g) {
      const unsigned long long m = __ballot(bkt == g);
      if (bkt == g) {
        const int leader = __ffsll(m) - 1;
        int base_;
        if (lane == leader) base_ = atomicAdd(&cursor[g], (int)__popcll(m));
        base_ = __shfl(base_, leader);
        pos = base_ + (int)__popcll(m & lt);
      }
    }
    if (pos >= 0) {
      kvS[pos] = kv;
      bucketOf[pos] = (unsigned char)bkt;
    }
  }
  __syncthreads();

  // reserve global space per group
  if (t < NGROUPS) {
    const int cnt = hist[t];
    gbase[t] = (cnt > 0) ? atomicAdd(&gCursor[t], cnt) : 0;
  }
  __syncthreads();

  // flush: 8 coalesced runs (~512 consecutive 8B records each)
  for (int i = t; i < nTot; i += 256) {
    const int bkt = bucketOf[i];
    gKV[(long long)gbase[bkt] + (i - base[bkt])] = kvS[i];
  }
}

// -------- kernel 6: XCD-partitioned edge-parallel scatter -------------------
// block b handles group b%8; round-robin block->XCD keeps each out-slice
// (1.6 MB) resident in one XCD's L2, so atomics coalesce in L2.
__global__ __launch_bounds__(256) void spmm8(
    const int* __restrict__ segStart, const unsigned long long* __restrict__ gKV,
    const float* __restrict__ support, float* __restrict__ out) {
  const int g = blockIdx.x & (NGROUPS - 1);
  const int jb = blockIdx.x >> 3;
  const int t = threadIdx.x;
  const int slot = t >> 5;   // 0..7 edge slots per block
  const int d = t & 31;      // output dim
  const int s = segStart[g];
  const int e = segStart[g + 1];
  const int rowBase = g * ROWS_PER_G;

  for (int i = s + jb * 8 + slot; i < e; i += BPG * 8) {
    const unsigned long long kv = gKV[i];
    const unsigned key = (unsigned)kv;
    const int c = (int)(key & 0x1FFFFu);
    const int row = rowBase + (int)(key >> 17);
    const float v = __uint_as_float((unsigned)(kv >> 32));
    atomicAdd(&out[(long long)row * OUT_DIM + d],
              v * support[(long long)c * OUT_DIM + d]);
  }
}

extern "C" void kernel_launch(void* const* d_in, const int* in_sizes, int n_in,
                              void* d_out, int out_size, void* d_ws, size_t ws_size,
                              hipStream_t stream) {
  const float* x        = (const float*)d_in[0];
  const int*   adj_rows = (const int*)d_in[1];
  const int*   adj_cols = (const int*)d_in[2];
  const float* adj_vals = (const float*)d_in[3];
  const float* weight   = (const float*)d_in[4];
  const float* bias     = (const float*)d_in[5];
  float* out = (float*)d_out;

  // ---- workspace layout (~25.6 MB) ----
  char* wsp = (char*)d_ws;
  float* support = (float*)wsp;                                    // 12,800,000 B
  unsigned long long* gKV = (unsigned long long*)(wsp + 12800000); // 12,800,000 B
  int* segStart = (int*)(wsp + 25600000);   // 9 ints
  int* gHist    = segStart + 16;            // 8 ints
  int* gCursor  = gHist + 16;               // 8 ints

  hipMemsetAsync(gHist, 0, NGROUPS * sizeof(int), stream);

  gemm_support<<<(N_NODES + 7) / 8, 256, 0, stream>>>(x, weight, support);
  init_out<<<(N_NODES * OUT_DIM + 255) / 256, 256, 0, stream>>>(bias, out);
  hist8<<<256, 256, 0, stream>>>(adj_rows, gHist);
  scan8<<<1, 64, 0, stream>>>(gHist, segStart, gCursor);
  bin8<<<(N_EDGES + EPB - 1) / EPB, 256, 0, stream>>>(
      adj_rows, adj_cols, adj_vals, gCursor, gKV);
  spmm8<<<NGROUPS * BPG, 256, 0, stream>>>(segStart, gKV, support, out);
}